// Round 1
// baseline (357.691 us; speedup 1.0000x reference)
//
#include <hip/hip_runtime.h>
#include <cstdint>

using u16 = unsigned short;
using u32 = unsigned int;

typedef __attribute__((ext_vector_type(8))) short short8;   // 8 bf16 (A/B frag)
typedef __attribute__((ext_vector_type(4))) float floatx4;  // C frag

__device__ __forceinline__ u16 f2bf(float f) {
    u32 u = __float_as_uint(f);
    u32 r = u + 0x7fffu + ((u >> 16) & 1u);   // round-to-nearest-even
    return (u16)(r >> 16);
}
__device__ __forceinline__ float bf2f(u16 h) {
    return __uint_as_float(((u32)h) << 16);
}

// ---------------------------------------------------------------- converts
__global__ void cvt_f32_to_bf16(const float* __restrict__ in, u16* __restrict__ out, long n) {
    long i = ((long)blockIdx.x * blockDim.x + threadIdx.x) * 4;
    if (i >= n) return;
    float4 v = *reinterpret_cast<const float4*>(in + i);
    uint2 o;
    o.x = (u32)f2bf(v.x) | ((u32)f2bf(v.y) << 16);
    o.y = (u32)f2bf(v.z) | ((u32)f2bf(v.w) << 16);
    *reinterpret_cast<uint2*>(out + i) = o;
}

__global__ void concat_bias(const float* __restrict__ a, const float* __restrict__ b,
                            float* __restrict__ out) {
    int i = blockIdx.x * 256 + threadIdx.x;   // 2048 threads
    out[i] = (i < 1024) ? a[i] : b[i - 1024];
}

// ---------------------------------------------------------------- GEMM (NT)
// C[m][n] = scale * sum_k A[m][k]*B[n][k] + bias_col[n] + bias_row[m]
// 128x128 tile, BK=32, 256 threads (4 waves, each 64x64 via 4x4 of 16x16x32 MFMA)
__device__ __forceinline__ void async_cp16(const u16* g, u16* l) {
    __builtin_amdgcn_global_load_lds(
        (const __attribute__((address_space(1))) void*)g,
        (__attribute__((address_space(3))) void*)l, 16, 0, 0);
}

template <bool BF16_OUT>
__global__ __launch_bounds__(256)
void gemm_nt(const u16* __restrict__ A, const u16* __restrict__ B, void* __restrict__ Cv,
             int K, int lda, int ldb, int ldc,
             long sA, long sB, long sC,
             const float* __restrict__ bias_col, const float* __restrict__ bias_row,
             float scale)
{
    const int bz = blockIdx.z;
    A += (long)bz * sA;
    B += (long)bz * sB;
    const long cbase = (long)bz * sC;

    __shared__ u16 As[128 * 32];
    __shared__ u16 Bs[128 * 32];

    const int tid  = threadIdx.x;
    const int lane = tid & 63;
    const int wave = tid >> 6;
    const int wm = (wave >> 1) << 6;   // wave row offset in tile
    const int wn = (wave & 1) << 6;    // wave col offset in tile

    const long tile_m = (long)blockIdx.y * 128;
    const long tile_n = (long)blockIdx.x * 128;

    floatx4 acc[4][4] = {};

    // staging: thread t loads 16B (8 bf16): row = t>>2, k-part = (t&3)*8
    const int srow = tid >> 2;
    const int skp  = (tid & 3) * 8;
    const u16* Ag = A + (tile_m + srow) * (long)lda + skp;
    const u16* Bg = B + (tile_n + srow) * (long)ldb + skp;
    u16* Asl = &As[tid * 8];           // byte offset tid*16 (wave-contiguous)
    u16* Bsl = &Bs[tid * 8];

    const int fm = lane & 15;
    const int fk = (lane >> 4) * 8;

    for (int k0 = 0; k0 < K; k0 += 32) {
        async_cp16(Ag,            Asl);
        async_cp16(Ag + 64 * (long)lda, Asl + 64 * 32);
        async_cp16(Bg,            Bsl);
        async_cp16(Bg + 64 * (long)ldb, Bsl + 64 * 32);
        Ag += 32; Bg += 32;
        __syncthreads();   // drains vmcnt (global_load_lds) + barrier

        short8 af[4], bfr[4];
        #pragma unroll
        for (int i = 0; i < 4; ++i)
            af[i] = *reinterpret_cast<const short8*>(&As[(wm + i * 16 + fm) * 32 + fk]);
        #pragma unroll
        for (int j = 0; j < 4; ++j)
            bfr[j] = *reinterpret_cast<const short8*>(&Bs[(wn + j * 16 + fm) * 32 + fk]);
        #pragma unroll
        for (int i = 0; i < 4; ++i)
            #pragma unroll
            for (int j = 0; j < 4; ++j)
                acc[i][j] = __builtin_amdgcn_mfma_f32_16x16x32_bf16(af[i], bfr[j], acc[i][j], 0, 0, 0);
        __syncthreads();
    }

    // epilogue: C/D layout col = lane&15, row = (lane>>4)*4 + r
    const int r0  = (lane >> 4) * 4;
    const int cn0 = lane & 15;
    #pragma unroll
    for (int i = 0; i < 4; ++i) {
        #pragma unroll
        for (int j = 0; j < 4; ++j) {
            long n = tile_n + wn + j * 16 + cn0;
            float bc = bias_col ? bias_col[n] : 0.0f;
            #pragma unroll
            for (int r = 0; r < 4; ++r) {
                long m = tile_m + wm + i * 16 + r0 + r;
                float v = acc[i][j][r] * scale + bc;
                if (bias_row) v += bias_row[m];
                long off = cbase + m * (long)ldc + n;
                if constexpr (BF16_OUT) ((u16*)Cv)[off] = f2bf(v);
                else                    ((float*)Cv)[off] = v;
            }
        }
    }
}

// ---------------------------------------------------------------- RoPE (in place on [8192][2048] = [Q|K])
__global__ void rope_kernel(u16* __restrict__ QK) {
    long idx = (long)blockIdx.x * 256 + threadIdx.x;  // pair index, 8192*1024 total
    long row = idx >> 10;
    int  p   = (int)(idx & 1023);
    int  i   = p & 511;            // pair idx within Q or K half
    int  s   = (int)(row & 2047);  // position in sequence
    // inv_freq = 10000^(-2i/1024)
    float inv = __expf((float)i * (-2.0f * 9.210340371976184f / 1024.0f));
    float ang = (float)s * inv;
    float sn, cs;
    sincosf(ang, &sn, &cs);
    u32* ptr = reinterpret_cast<u32*>(&QK[row * 2048 + p * 2]);
    u32 v = *ptr;
    float x0 = bf2f((u16)(v & 0xffffu));
    float x1 = bf2f((u16)(v >> 16));
    float o0 = x0 * cs - x1 * sn;
    float o1 = x0 * sn + x1 * cs;
    *ptr = (u32)f2bf(o0) | ((u32)f2bf(o1) << 16);
}

// ---------------------------------------------------------------- softmax rows of 2048
__global__ __launch_bounds__(256)
void softmax_kernel(const float* __restrict__ S, u16* __restrict__ P) {
    long row = blockIdx.x;
    const float* s = S + row * 2048;
    u16* p = P + row * 2048;
    int tid = threadIdx.x;
    float4 a = reinterpret_cast<const float4*>(s)[tid * 2];
    float4 b = reinterpret_cast<const float4*>(s)[tid * 2 + 1];
    float v[8] = {a.x, a.y, a.z, a.w, b.x, b.y, b.z, b.w};
    float mx = v[0];
    #pragma unroll
    for (int j = 1; j < 8; ++j) mx = fmaxf(mx, v[j]);
    #pragma unroll
    for (int off = 32; off; off >>= 1) mx = fmaxf(mx, __shfl_xor(mx, off));
    __shared__ float redm[4];
    __shared__ float reds[4];
    int lane = tid & 63, wv = tid >> 6;
    if (lane == 0) redm[wv] = mx;
    __syncthreads();
    mx = fmaxf(fmaxf(redm[0], redm[1]), fmaxf(redm[2], redm[3]));
    float sum = 0.0f;
    #pragma unroll
    for (int j = 0; j < 8; ++j) { v[j] = __expf(v[j] - mx); sum += v[j]; }
    #pragma unroll
    for (int off = 32; off; off >>= 1) sum += __shfl_xor(sum, off);
    if (lane == 0) reds[wv] = sum;
    __syncthreads();
    sum = reds[0] + reds[1] + reds[2] + reds[3];
    float inv = 1.0f / sum;
    uint4 o;
    o.x = (u32)f2bf(v[0] * inv) | ((u32)f2bf(v[1] * inv) << 16);
    o.y = (u32)f2bf(v[2] * inv) | ((u32)f2bf(v[3] * inv) << 16);
    o.z = (u32)f2bf(v[4] * inv) | ((u32)f2bf(v[5] * inv) << 16);
    o.w = (u32)f2bf(v[6] * inv) | ((u32)f2bf(v[7] * inv) << 16);
    *reinterpret_cast<uint4*>(&p[tid * 8]) = o;
}

// ---------------------------------------------------------------- launch
extern "C" void kernel_launch(void* const* d_in, const int* in_sizes, int n_in,
                              void* d_out, int out_size, void* d_ws, size_t ws_size,
                              hipStream_t stream)
{
    const float* x   = (const float*)d_in[0];
    const float* wqw = (const float*)d_in[1];
    const float* wqb = (const float*)d_in[2];
    const float* wkw = (const float*)d_in[3];
    const float* wkb = (const float*)d_in[4];
    const float* wvw = (const float*)d_in[5];
    const float* wvb = (const float*)d_in[6];
    float* out = (float*)d_out;

    char* ws = (char*)d_ws;
    const size_t MB = 1ull << 20;
    // late-phase buffers
    float* Sbuf = (float*)(ws + 0);          // 64MB [4][2048][2048] f32  (written at G3)
    u16*   Pbuf = (u16*)(ws + 64 * MB);      // 32MB [4][2048][2048] bf16
    u16*   QK   = (u16*)(ws + 96 * MB);      // 32MB [8192][2048] bf16 (Q cols 0..1023, K cols 1024..2047)
    u16*   VT   = (u16*)(ws + 128 * MB);     // 16MB [4][1024][2048] bf16 (V transposed)
    // early-phase buffers (overlap Sbuf region; dead before G3 writes S)
    u16*   xb    = (u16*)(ws + 0);           // 16MB [8192][1024]
    u16*   wqk   = (u16*)(ws + 16 * MB);     //  4MB [2048][1024]
    u16*   wvbuf = (u16*)(ws + 20 * MB);     //  2MB [1024][1024]
    float* bqk   = (float*)(ws + 22 * MB);   //  8KB [2048]

    // 1. dtype conversion
    cvt_f32_to_bf16<<<dim3(8192), 256, 0, stream>>>(x, xb, 8192L * 1024);
    cvt_f32_to_bf16<<<dim3(1024), 256, 0, stream>>>(wqw, wqk, 1024L * 1024);
    cvt_f32_to_bf16<<<dim3(1024), 256, 0, stream>>>(wkw, wqk + 1024 * 1024, 1024L * 1024);
    cvt_f32_to_bf16<<<dim3(1024), 256, 0, stream>>>(wvw, wvbuf, 1024L * 1024);
    concat_bias<<<dim3(8), 256, 0, stream>>>(wqb, wkb, bqk);

    // 2. G1: [Q|K] = xb @ wqk^T + bqk   (M=8192, N=2048, K=1024)
    gemm_nt<true><<<dim3(16, 64, 1), 256, 0, stream>>>(
        xb, wqk, QK, 1024, 1024, 1024, 2048,
        0L, 0L, 0L, bqk, nullptr, 1.0f);

    // 3. G2: VT[b] = wv @ xb[b]^T + bv[row]   (M=1024, N=2048, K=1024, z=4)
    gemm_nt<true><<<dim3(16, 8, 4), 256, 0, stream>>>(
        wvbuf, xb, VT, 1024, 1024, 1024, 2048,
        0L, 2048L * 1024, 1024L * 2048, nullptr, wvb, 1.0f);

    // 4. RoPE in place on [Q|K]
    rope_kernel<<<dim3(32768), 256, 0, stream>>>(QK);

    // 5. G3: S[b] = Q[b] @ K[b]^T / 32   (M=N=2048, K=1024, z=4)
    gemm_nt<false><<<dim3(16, 16, 4), 256, 0, stream>>>(
        QK, QK + 1024, Sbuf, 1024, 2048, 2048, 2048,
        2048L * 2048, 2048L * 2048, 2048L * 2048, nullptr, nullptr, 0.03125f);

    // 6. softmax rows -> P bf16
    softmax_kernel<<<dim3(8192), 256, 0, stream>>>(Sbuf, Pbuf);

    // 7. G5: out[b] = P[b] @ VT[b]^T   (M=2048, N=1024, K=2048, z=4)
    gemm_nt<false><<<dim3(8, 16, 4), 256, 0, stream>>>(
        Pbuf, VT, out, 2048, 2048, 2048, 1024,
        2048L * 2048, 1024L * 2048, 2048L * 1024, nullptr, nullptr, 1.0f);

    (void)in_sizes; (void)n_in; (void)out_size; (void)ws_size;
}

// Round 2
// 332.079 us; speedup vs baseline: 1.0771x; 1.0771x over previous
//
#include <hip/hip_runtime.h>
#include <cstdint>

using u16 = unsigned short;
using u32 = unsigned int;

typedef __attribute__((ext_vector_type(8))) short short8;   // 8 bf16 (A/B frag)
typedef __attribute__((ext_vector_type(4))) float floatx4;  // C frag

__device__ __forceinline__ u16 f2bf(float f) {
    u32 u = __float_as_uint(f);
    u32 r = u + 0x7fffu + ((u >> 16) & 1u);   // round-to-nearest-even
    return (u16)(r >> 16);
}
__device__ __forceinline__ float bf2f(u16 h) {
    return __uint_as_float(((u32)h) << 16);
}

// ---------------------------------------------------------------- converts
__global__ void cvt_f32_to_bf16(const float* __restrict__ in, u16* __restrict__ out, long n) {
    long i = ((long)blockIdx.x * blockDim.x + threadIdx.x) * 4;
    if (i >= n) return;
    float4 v = *reinterpret_cast<const float4*>(in + i);
    uint2 o;
    o.x = (u32)f2bf(v.x) | ((u32)f2bf(v.y) << 16);
    o.y = (u32)f2bf(v.z) | ((u32)f2bf(v.w) << 16);
    *reinterpret_cast<uint2*>(out + i) = o;
}

// three 1024x1024 weight matrices in one dispatch
__global__ void cvt3(const float* __restrict__ w0, const float* __restrict__ w1,
                     const float* __restrict__ w2,
                     u16* __restrict__ o0, u16* __restrict__ o1, u16* __restrict__ o2) {
    int b = blockIdx.x;            // 3072 blocks
    int seg = b >> 10;
    const float* src; u16* dst;
    if (seg == 0)      { src = w0; dst = o0; }
    else if (seg == 1) { src = w1; dst = o1; }
    else               { src = w2; dst = o2; }
    long i = ((long)(b & 1023) * 256 + threadIdx.x) * 4;
    float4 v = *reinterpret_cast<const float4*>(src + i);
    uint2 o;
    o.x = (u32)f2bf(v.x) | ((u32)f2bf(v.y) << 16);
    o.y = (u32)f2bf(v.z) | ((u32)f2bf(v.w) << 16);
    *reinterpret_cast<uint2*>(dst + i) = o;
}

__global__ void concat_bias(const float* __restrict__ a, const float* __restrict__ b,
                            float* __restrict__ out) {
    int i = blockIdx.x * 256 + threadIdx.x;   // 2048 threads
    out[i] = (i < 1024) ? a[i] : b[i - 1024];
}

// ---------------------------------------------------------------- GEMM (NT)
// C[m][n] = scale * sum_k A[m][k]*B[n][k] + bias_col[n] + bias_row[m], optional fused RoPE
// 128x128 tile, BK=32, 256 threads (4 waves, each 64x64 via 4x4 of 16x16x32 MFMA)
__device__ __forceinline__ void async_cp16(const u16* g, u16* l) {
    __builtin_amdgcn_global_load_lds(
        (const __attribute__((address_space(1))) void*)g,
        (__attribute__((address_space(3))) void*)l, 16, 0, 0);
}

template <bool BF16_OUT, bool ROPE>
__global__ __launch_bounds__(256)
void gemm_nt(const u16* __restrict__ A, const u16* __restrict__ B, void* __restrict__ Cv,
             int K, int lda, int ldb, int ldc,
             long sA, long sB, long sC,
             const float* __restrict__ bias_col, const float* __restrict__ bias_row,
             float scale)
{
    const int bz = blockIdx.z;
    A += (long)bz * sA;
    B += (long)bz * sB;
    const long cbase = (long)bz * sC;

    // LDS: K-loop staging (16KB) unioned with epilogue transpose buffer (4 waves x 16 x 68 f32)
    __shared__ alignas(16) float smemf[4 * 16 * 68];   // 17408 B
    u16* As = (u16*)smemf;            // 128*32 u16 = 8KB
    u16* Bs = As + 128 * 32;          // 8KB

    const int tid  = threadIdx.x;
    const int lane = tid & 63;
    const int wave = tid >> 6;
    const int wm = (wave >> 1) << 6;   // wave row offset in tile
    const int wn = (wave & 1) << 6;    // wave col offset in tile

    const long tile_m = (long)blockIdx.y * 128;
    const long tile_n = (long)blockIdx.x * 128;

    floatx4 acc[4][4] = {};

    // staging: thread t loads 16B (8 bf16): row = t>>2, k-part = (t&3)*8
    const int srow = tid >> 2;
    const int skp  = (tid & 3) * 8;
    const u16* Ag = A + (tile_m + srow) * (long)lda + skp;
    const u16* Bg = B + (tile_n + srow) * (long)ldb + skp;
    u16* Asl = &As[tid * 8];           // wave-contiguous (global_load_lds requirement)
    u16* Bsl = &Bs[tid * 8];

    const int fm = lane & 15;
    const int fk = (lane >> 4) * 8;

    for (int k0 = 0; k0 < K; k0 += 32) {
        async_cp16(Ag,                  Asl);
        async_cp16(Ag + 64 * (long)lda, Asl + 64 * 32);
        async_cp16(Bg,                  Bsl);
        async_cp16(Bg + 64 * (long)ldb, Bsl + 64 * 32);
        Ag += 32; Bg += 32;
        __syncthreads();   // drains vmcnt (global_load_lds) + barrier

        short8 af[4], bfr[4];
        #pragma unroll
        for (int i = 0; i < 4; ++i)
            af[i] = *reinterpret_cast<const short8*>(&As[(wm + i * 16 + fm) * 32 + fk]);
        #pragma unroll
        for (int j = 0; j < 4; ++j)
            bfr[j] = *reinterpret_cast<const short8*>(&Bs[(wn + j * 16 + fm) * 32 + fk]);
        #pragma unroll
        for (int i = 0; i < 4; ++i)
            #pragma unroll
            for (int j = 0; j < 4; ++j)
                acc[i][j] = __builtin_amdgcn_mfma_f32_16x16x32_bf16(af[i], bfr[j], acc[i][j], 0, 0, 0);
        __syncthreads();
    }

    // ---------------- epilogue: LDS transpose -> vectorized stores ----------------
    // C/D layout: col = lane&15, row = (lane>>4)*4 + r
    const int q4  = lane >> 4;
    const int c16 = lane & 15;
    float* myeps = smemf + wave * (16 * 68);
    const long n0 = tile_n + wn + c16 * 4;    // 4 consecutive columns per lane (lane-constant)

    float4 bc4 = make_float4(0.f, 0.f, 0.f, 0.f);
    if (bias_col) bc4 = *reinterpret_cast<const float4*>(bias_col + n0);

    float inv0 = 0.f, inv1 = 0.f;
    if constexpr (ROPE) {
        // inv_freq = 10000^(-i/512); pair index i = ((n>>1) & 511), lane-constant
        int p0 = (int)(n0 >> 1);
        inv0 = __expf((float)(p0 & 511)       * -1.79889463e-2f);
        inv1 = __expf((float)((p0 + 1) & 511) * -1.79889463e-2f);
    }

    #pragma unroll
    for (int i = 0; i < 4; ++i) {
        __syncthreads();   // protect As/Bs (first) / previous chunk reads
        #pragma unroll
        for (int j = 0; j < 4; ++j)
            #pragma unroll
            for (int r = 0; r < 4; ++r)
                myeps[(q4 * 4 + r) * 68 + j * 16 + c16] = acc[i][j][r];
        __syncthreads();
        #pragma unroll
        for (int p = 0; p < 4; ++p) {
            int lrow = p * 4 + q4;
            long m = tile_m + wm + i * 16 + lrow;
            float4 v = *reinterpret_cast<const float4*>(&myeps[lrow * 68 + c16 * 4]);
            v.x = v.x * scale + bc4.x;
            v.y = v.y * scale + bc4.y;
            v.z = v.z * scale + bc4.z;
            v.w = v.w * scale + bc4.w;
            if (bias_row) {
                float br = bias_row[m];
                v.x += br; v.y += br; v.z += br; v.w += br;
            }
            if constexpr (ROPE) {
                int s = (int)(m & 2047);
                float a0 = (float)s * inv0, a1 = (float)s * inv1;
                float sn0 = __sinf(a0), cs0 = __cosf(a0);
                float sn1 = __sinf(a1), cs1 = __cosf(a1);
                float x0 = v.x, x1 = v.y, x2 = v.z, x3 = v.w;
                v.x = x0 * cs0 - x1 * sn0;
                v.y = x0 * sn0 + x1 * cs0;
                v.z = x2 * cs1 - x3 * sn1;
                v.w = x2 * sn1 + x3 * cs1;
            }
            long off = cbase + m * (long)ldc + n0;
            if constexpr (BF16_OUT) {
                uint2 o;
                o.x = (u32)f2bf(v.x) | ((u32)f2bf(v.y) << 16);
                o.y = (u32)f2bf(v.z) | ((u32)f2bf(v.w) << 16);
                *reinterpret_cast<uint2*>((u16*)Cv + off) = o;
            } else {
                *reinterpret_cast<float4*>((float*)Cv + off) = v;
            }
        }
    }
}

// ---------------------------------------------------------------- softmax rows of 2048
__global__ __launch_bounds__(256)
void softmax_kernel(const float* __restrict__ S, u16* __restrict__ P) {
    long row = blockIdx.x;
    const float* s = S + row * 2048;
    u16* p = P + row * 2048;
    int tid = threadIdx.x;
    float4 a = reinterpret_cast<const float4*>(s)[tid * 2];
    float4 b = reinterpret_cast<const float4*>(s)[tid * 2 + 1];
    float v[8] = {a.x, a.y, a.z, a.w, b.x, b.y, b.z, b.w};
    float mx = v[0];
    #pragma unroll
    for (int j = 1; j < 8; ++j) mx = fmaxf(mx, v[j]);
    #pragma unroll
    for (int off = 32; off; off >>= 1) mx = fmaxf(mx, __shfl_xor(mx, off));
    __shared__ float redm[4];
    __shared__ float reds[4];
    int lane = tid & 63, wv = tid >> 6;
    if (lane == 0) redm[wv] = mx;
    __syncthreads();
    mx = fmaxf(fmaxf(redm[0], redm[1]), fmaxf(redm[2], redm[3]));
    float sum = 0.0f;
    #pragma unroll
    for (int j = 0; j < 8; ++j) { v[j] = __expf(v[j] - mx); sum += v[j]; }
    #pragma unroll
    for (int off = 32; off; off >>= 1) sum += __shfl_xor(sum, off);
    if (lane == 0) reds[wv] = sum;
    __syncthreads();
    sum = reds[0] + reds[1] + reds[2] + reds[3];
    float inv = 1.0f / sum;
    uint4 o;
    o.x = (u32)f2bf(v[0] * inv) | ((u32)f2bf(v[1] * inv) << 16);
    o.y = (u32)f2bf(v[2] * inv) | ((u32)f2bf(v[3] * inv) << 16);
    o.z = (u32)f2bf(v[4] * inv) | ((u32)f2bf(v[5] * inv) << 16);
    o.w = (u32)f2bf(v[6] * inv) | ((u32)f2bf(v[7] * inv) << 16);
    *reinterpret_cast<uint4*>(&p[tid * 8]) = o;
}

// ---------------------------------------------------------------- launch
extern "C" void kernel_launch(void* const* d_in, const int* in_sizes, int n_in,
                              void* d_out, int out_size, void* d_ws, size_t ws_size,
                              hipStream_t stream)
{
    const float* x   = (const float*)d_in[0];
    const float* wqw = (const float*)d_in[1];
    const float* wqb = (const float*)d_in[2];
    const float* wkw = (const float*)d_in[3];
    const float* wkb = (const float*)d_in[4];
    const float* wvw = (const float*)d_in[5];
    const float* wvb = (const float*)d_in[6];
    float* out = (float*)d_out;

    char* ws = (char*)d_ws;
    const size_t MB = 1ull << 20;
    // late-phase buffers
    float* Sbuf = (float*)(ws + 0);          // 64MB [4][2048][2048] f32  (written at G3)
    u16*   Pbuf = (u16*)(ws + 64 * MB);      // 32MB [4][2048][2048] bf16
    u16*   QK   = (u16*)(ws + 96 * MB);      // 32MB [8192][2048] bf16 (Q | K), RoPE applied
    u16*   VT   = (u16*)(ws + 128 * MB);     // 16MB [4][1024][2048] bf16 (V transposed)
    // early-phase buffers (overlap Sbuf region; dead before G3 writes S)
    u16*   xb    = (u16*)(ws + 0);           // 16MB [8192][1024]
    u16*   wqk   = (u16*)(ws + 16 * MB);     //  4MB [2048][1024]
    u16*   wvbuf = (u16*)(ws + 20 * MB);     //  2MB [1024][1024]
    float* bqk   = (float*)(ws + 22 * MB);   //  8KB [2048]

    // 1. dtype conversion
    cvt_f32_to_bf16<<<dim3(8192), 256, 0, stream>>>(x, xb, 8192L * 1024);
    cvt3<<<dim3(3072), 256, 0, stream>>>(wqw, wkw, wvw, wqk, wqk + 1024 * 1024, wvbuf);
    concat_bias<<<dim3(8), 256, 0, stream>>>(wqb, wkb, bqk);

    // 2. G1: [Q|K] = xb @ wqk^T + bqk, RoPE fused in epilogue  (M=8192, N=2048, K=1024)
    gemm_nt<true, true><<<dim3(16, 64, 1), 256, 0, stream>>>(
        xb, wqk, QK, 1024, 1024, 1024, 2048,
        0L, 0L, 0L, bqk, nullptr, 1.0f);

    // 3. G2: VT[b] = wv @ xb[b]^T + bv[row]   (M=1024, N=2048, K=1024, z=4)
    gemm_nt<true, false><<<dim3(16, 8, 4), 256, 0, stream>>>(
        wvbuf, xb, VT, 1024, 1024, 1024, 2048,
        0L, 2048L * 1024, 1024L * 2048, nullptr, wvb, 1.0f);

    // 4. G3: S[b] = Q[b] @ K[b]^T / 32   (M=N=2048, K=1024, z=4)
    gemm_nt<false, false><<<dim3(16, 16, 4), 256, 0, stream>>>(
        QK, QK + 1024, Sbuf, 1024, 2048, 2048, 2048,
        2048L * 2048, 2048L * 2048, 2048L * 2048, nullptr, nullptr, 0.03125f);

    // 5. softmax rows -> P bf16
    softmax_kernel<<<dim3(8192), 256, 0, stream>>>(Sbuf, Pbuf);

    // 6. G5: out[b] = P[b] @ VT[b]^T   (M=2048, N=1024, K=2048, z=4)
    gemm_nt<false, false><<<dim3(8, 16, 4), 256, 0, stream>>>(
        Pbuf, VT, out, 2048, 2048, 2048, 1024,
        2048L * 2048, 1024L * 2048, 2048L * 1024, nullptr, nullptr, 1.0f);

    (void)in_sizes; (void)n_in; (void)out_size; (void)ws_size;
}

// Round 3
// 298.303 us; speedup vs baseline: 1.1991x; 1.1132x over previous
//
#include <hip/hip_runtime.h>
#include <cstdint>

using u16 = unsigned short;
using u32 = unsigned int;

typedef __attribute__((ext_vector_type(8))) short short8;   // 8 bf16 (A/B frag)
typedef __attribute__((ext_vector_type(4))) float floatx4;  // C frag

__device__ __forceinline__ u16 f2bf(float f) {
    u32 u = __float_as_uint(f);
    u32 r = u + 0x7fffu + ((u >> 16) & 1u);   // round-to-nearest-even
    return (u16)(r >> 16);
}

// ---------------------------------------------------------------- converts
__global__ void cvt_f32_to_bf16(const float* __restrict__ in, u16* __restrict__ out, long n) {
    long i = ((long)blockIdx.x * blockDim.x + threadIdx.x) * 4;
    if (i >= n) return;
    float4 v = *reinterpret_cast<const float4*>(in + i);
    uint2 o;
    o.x = (u32)f2bf(v.x) | ((u32)f2bf(v.y) << 16);
    o.y = (u32)f2bf(v.z) | ((u32)f2bf(v.w) << 16);
    *reinterpret_cast<uint2*>(out + i) = o;
}

// three 1024x1024 weight matrices in one dispatch
__global__ void cvt3(const float* __restrict__ w0, const float* __restrict__ w1,
                     const float* __restrict__ w2,
                     u16* __restrict__ o0, u16* __restrict__ o1, u16* __restrict__ o2) {
    int b = blockIdx.x;            // 3072 blocks
    int seg = b >> 10;
    const float* src; u16* dst;
    if (seg == 0)      { src = w0; dst = o0; }
    else if (seg == 1) { src = w1; dst = o1; }
    else               { src = w2; dst = o2; }
    long i = ((long)(b & 1023) * 256 + threadIdx.x) * 4;
    float4 v = *reinterpret_cast<const float4*>(src + i);
    uint2 o;
    o.x = (u32)f2bf(v.x) | ((u32)f2bf(v.y) << 16);
    o.y = (u32)f2bf(v.z) | ((u32)f2bf(v.w) << 16);
    *reinterpret_cast<uint2*>(dst + i) = o;
}

__global__ void concat_bias(const float* __restrict__ a, const float* __restrict__ b,
                            float* __restrict__ out) {
    int i = blockIdx.x * 256 + threadIdx.x;   // 2048 threads
    out[i] = (i < 1024) ? a[i] : b[i - 1024];
}

// ---------------------------------------------------------------- GEMM (NT)
// C[m][n] = scale * sum_k A[m][k]*B[n][k] + bias_col[n] + bias_row[m], optional fused RoPE
// 128x128 tile, BK=64 (two 32-wide LDS panels), 256 threads,
// 4 waves each 64x64 via 4x4 of 16x16x32 MFMA, 2 k-chunks per barrier pair.
__device__ __forceinline__ void async_cp16(const u16* g, u16* l) {
    __builtin_amdgcn_global_load_lds(
        (const __attribute__((address_space(1))) void*)g,
        (__attribute__((address_space(3))) void*)l, 16, 0, 0);
}

template <bool BF16_OUT, bool ROPE>
__global__ __launch_bounds__(256)
void gemm_nt(const u16* __restrict__ A, const u16* __restrict__ B, void* __restrict__ Cv,
             int K, int lda, int ldb, int ldc,
             long sA, long sB, long sC,
             const float* __restrict__ bias_col, const float* __restrict__ bias_row,
             float scale)
{
    const int bz = blockIdx.z;
    A += (long)bz * sA;
    B += (long)bz * sB;
    const long cbase = (long)bz * sC;

    // LDS 32KB: A = 2 panels of [128][32] u16, B likewise. Epilogue transpose
    // buffer (4 waves x 16 x 68 f32 = 17.4KB) aliases the same memory.
    __shared__ alignas(16) u16 smem[16384];
    u16* As = smem;                 // panels: As + p*4096
    u16* Bs = smem + 8192;

    const int tid  = threadIdx.x;
    const int lane = tid & 63;
    const int wave = tid >> 6;
    const int wm = (wave >> 1) << 6;   // wave row offset in tile
    const int wn = (wave & 1) << 6;    // wave col offset in tile

    const long tile_m = (long)blockIdx.y * 128;
    const long tile_n = (long)blockIdx.x * 128;

    floatx4 acc[4][4] = {};

    // staging: thread t loads 16B (8 bf16): row = t>>2, k-part = (t&3)*8 within a panel
    const int srow = tid >> 2;
    const int skp  = (tid & 3) * 8;
    const u16* Ag = A + (tile_m + srow) * (long)lda + skp;
    const u16* Bg = B + (tile_n + srow) * (long)ldb + skp;
    u16* Asl = &As[tid * 8];           // wave-contiguous (global_load_lds requirement)
    u16* Bsl = &Bs[tid * 8];

    const int fm = lane & 15;
    const int fk = (lane >> 4) * 8;

    for (int k0 = 0; k0 < K; k0 += 64) {
        // panel 0 (k0..k0+31) and panel 1 (k0+32..k0+63): 8 async 16B copies
        async_cp16(Ag,                       Asl);
        async_cp16(Ag + 64 * (long)lda,      Asl + 64 * 32);
        async_cp16(Ag + 32,                  Asl + 4096);
        async_cp16(Ag + 32 + 64 * (long)lda, Asl + 4096 + 64 * 32);
        async_cp16(Bg,                       Bsl);
        async_cp16(Bg + 64 * (long)ldb,      Bsl + 64 * 32);
        async_cp16(Bg + 32,                  Bsl + 4096);
        async_cp16(Bg + 32 + 64 * (long)ldb, Bsl + 4096 + 64 * 32);
        Ag += 64; Bg += 64;
        __syncthreads();   // one vmcnt drain + barrier per 32 MFMA

        #pragma unroll
        for (int c = 0; c < 2; ++c) {
            const u16* Ap = As + c * 4096;
            const u16* Bp = Bs + c * 4096;
            short8 af[4], bfr[4];
            #pragma unroll
            for (int i = 0; i < 4; ++i)
                af[i] = *reinterpret_cast<const short8*>(&Ap[(wm + i * 16 + fm) * 32 + fk]);
            #pragma unroll
            for (int j = 0; j < 4; ++j)
                bfr[j] = *reinterpret_cast<const short8*>(&Bp[(wn + j * 16 + fm) * 32 + fk]);
            #pragma unroll
            for (int i = 0; i < 4; ++i)
                #pragma unroll
                for (int j = 0; j < 4; ++j)
                    acc[i][j] = __builtin_amdgcn_mfma_f32_16x16x32_bf16(af[i], bfr[j], acc[i][j], 0, 0, 0);
        }
        __syncthreads();
    }

    // ---------------- epilogue: LDS transpose -> vectorized stores ----------------
    // C/D layout: col = lane&15, row = (lane>>4)*4 + r
    const int q4  = lane >> 4;
    const int c16 = lane & 15;
    float* smemf  = (float*)smem;
    float* myeps = smemf + wave * (16 * 68);
    const long n0 = tile_n + wn + c16 * 4;    // 4 consecutive columns per lane (lane-constant)

    float4 bc4 = make_float4(0.f, 0.f, 0.f, 0.f);
    if (bias_col) bc4 = *reinterpret_cast<const float4*>(bias_col + n0);

    float inv0 = 0.f, inv1 = 0.f;
    if constexpr (ROPE) {
        // inv_freq = 10000^(-i/512); pair index i = ((n>>1) & 511), lane-constant
        int p0 = (int)(n0 >> 1);
        inv0 = __expf((float)(p0 & 511)       * -1.79889463e-2f);
        inv1 = __expf((float)((p0 + 1) & 511) * -1.79889463e-2f);
    }

    #pragma unroll
    for (int i = 0; i < 4; ++i) {
        __syncthreads();   // protect As/Bs (first) / previous chunk reads
        #pragma unroll
        for (int j = 0; j < 4; ++j)
            #pragma unroll
            for (int r = 0; r < 4; ++r)
                myeps[(q4 * 4 + r) * 68 + j * 16 + c16] = acc[i][j][r];
        __syncthreads();
        #pragma unroll
        for (int p = 0; p < 4; ++p) {
            int lrow = p * 4 + q4;
            long m = tile_m + wm + i * 16 + lrow;
            float4 v = *reinterpret_cast<const float4*>(&myeps[lrow * 68 + c16 * 4]);
            v.x = v.x * scale + bc4.x;
            v.y = v.y * scale + bc4.y;
            v.z = v.z * scale + bc4.z;
            v.w = v.w * scale + bc4.w;
            if (bias_row) {
                float br = bias_row[m];
                v.x += br; v.y += br; v.z += br; v.w += br;
            }
            if constexpr (ROPE) {
                int s = (int)(m & 2047);
                float a0 = (float)s * inv0, a1 = (float)s * inv1;
                float sn0 = __sinf(a0), cs0 = __cosf(a0);
                float sn1 = __sinf(a1), cs1 = __cosf(a1);
                float x0 = v.x, x1 = v.y, x2 = v.z, x3 = v.w;
                v.x = x0 * cs0 - x1 * sn0;
                v.y = x0 * sn0 + x1 * cs0;
                v.z = x2 * cs1 - x3 * sn1;
                v.w = x2 * sn1 + x3 * cs1;
            }
            long off = cbase + m * (long)ldc + n0;
            if constexpr (BF16_OUT) {
                uint2 o;
                o.x = (u32)f2bf(v.x) | ((u32)f2bf(v.y) << 16);
                o.y = (u32)f2bf(v.z) | ((u32)f2bf(v.w) << 16);
                *reinterpret_cast<uint2*>((u16*)Cv + off) = o;
            } else {
                *reinterpret_cast<float4*>((float*)Cv + off) = v;
            }
        }
    }
}

// ---------------------------------------------------------------- softmax rows of 2048
__global__ __launch_bounds__(256)
void softmax_kernel(const float* __restrict__ S, u16* __restrict__ P) {
    long row = blockIdx.x;
    const float* s = S + row * 2048;
    u16* p = P + row * 2048;
    int tid = threadIdx.x;
    float4 a = reinterpret_cast<const float4*>(s)[tid * 2];
    float4 b = reinterpret_cast<const float4*>(s)[tid * 2 + 1];
    float v[8] = {a.x, a.y, a.z, a.w, b.x, b.y, b.z, b.w};
    float mx = v[0];
    #pragma unroll
    for (int j = 1; j < 8; ++j) mx = fmaxf(mx, v[j]);
    #pragma unroll
    for (int off = 32; off; off >>= 1) mx = fmaxf(mx, __shfl_xor(mx, off));
    __shared__ float redm[4];
    __shared__ float reds[4];
    int lane = tid & 63, wv = tid >> 6;
    if (lane == 0) redm[wv] = mx;
    __syncthreads();
    mx = fmaxf(fmaxf(redm[0], redm[1]), fmaxf(redm[2], redm[3]));
    float sum = 0.0f;
    #pragma unroll
    for (int j = 0; j < 8; ++j) { v[j] = __expf(v[j] - mx); sum += v[j]; }
    #pragma unroll
    for (int off = 32; off; off >>= 1) sum += __shfl_xor(sum, off);
    if (lane == 0) reds[wv] = sum;
    __syncthreads();
    sum = reds[0] + reds[1] + reds[2] + reds[3];
    float inv = 1.0f / sum;
    uint4 o;
    o.x = (u32)f2bf(v[0] * inv) | ((u32)f2bf(v[1] * inv) << 16);
    o.y = (u32)f2bf(v[2] * inv) | ((u32)f2bf(v[3] * inv) << 16);
    o.z = (u32)f2bf(v[4] * inv) | ((u32)f2bf(v[5] * inv) << 16);
    o.w = (u32)f2bf(v[6] * inv) | ((u32)f2bf(v[7] * inv) << 16);
    *reinterpret_cast<uint4*>(&p[tid * 8]) = o;
}

// ---------------------------------------------------------------- launch
extern "C" void kernel_launch(void* const* d_in, const int* in_sizes, int n_in,
                              void* d_out, int out_size, void* d_ws, size_t ws_size,
                              hipStream_t stream)
{
    const float* x   = (const float*)d_in[0];
    const float* wqw = (const float*)d_in[1];
    const float* wqb = (const float*)d_in[2];
    const float* wkw = (const float*)d_in[3];
    const float* wkb = (const float*)d_in[4];
    const float* wvw = (const float*)d_in[5];
    const float* wvb = (const float*)d_in[6];
    float* out = (float*)d_out;

    char* ws = (char*)d_ws;
    const size_t MB = 1ull << 20;
    // late-phase buffers
    float* Sbuf = (float*)(ws + 0);          // 64MB [4][2048][2048] f32  (written at G3)
    u16*   Pbuf = (u16*)(ws + 64 * MB);      // 32MB [4][2048][2048] bf16
    u16*   QK   = (u16*)(ws + 96 * MB);      // 32MB [8192][2048] bf16 (Q | K), RoPE applied
    u16*   VT   = (u16*)(ws + 128 * MB);     // 16MB [4][1024][2048] bf16 (V transposed)
    // early-phase buffers (overlap Sbuf region; dead before G3 writes S)
    u16*   xb    = (u16*)(ws + 0);           // 16MB [8192][1024]
    u16*   wqk   = (u16*)(ws + 16 * MB);     //  4MB [2048][1024]
    u16*   wvbuf = (u16*)(ws + 20 * MB);     //  2MB [1024][1024]
    float* bqk   = (float*)(ws + 22 * MB);   //  8KB [2048]

    // 1. dtype conversion
    cvt_f32_to_bf16<<<dim3(8192), 256, 0, stream>>>(x, xb, 8192L * 1024);
    cvt3<<<dim3(3072), 256, 0, stream>>>(wqw, wkw, wvw, wqk, wqk + 1024 * 1024, wvbuf);
    concat_bias<<<dim3(8), 256, 0, stream>>>(wqb, wkb, bqk);

    // 2. G1: [Q|K] = xb @ wqk^T + bqk, RoPE fused in epilogue  (M=8192, N=2048, K=1024)
    gemm_nt<true, true><<<dim3(16, 64, 1), 256, 0, stream>>>(
        xb, wqk, QK, 1024, 1024, 1024, 2048,
        0L, 0L, 0L, bqk, nullptr, 1.0f);

    // 3. G2: VT[b] = wv @ xb[b]^T + bv[row]   (M=1024, N=2048, K=1024, z=4)
    gemm_nt<true, false><<<dim3(16, 8, 4), 256, 0, stream>>>(
        wvbuf, xb, VT, 1024, 1024, 1024, 2048,
        0L, 2048L * 1024, 1024L * 2048, nullptr, wvb, 1.0f);

    // 4. G3: S[b] = Q[b] @ K[b]^T / 32   (M=N=2048, K=1024, z=4)
    gemm_nt<false, false><<<dim3(16, 16, 4), 256, 0, stream>>>(
        QK, QK + 1024, Sbuf, 1024, 2048, 2048, 2048,
        2048L * 2048, 2048L * 2048, 2048L * 2048, nullptr, nullptr, 0.03125f);

    // 5. softmax rows -> P bf16
    softmax_kernel<<<dim3(8192), 256, 0, stream>>>(Sbuf, Pbuf);

    // 6. G5: out[b] = P[b] @ VT[b]^T   (M=2048, N=1024, K=2048, z=4)
    gemm_nt<false, false><<<dim3(8, 16, 4), 256, 0, stream>>>(
        Pbuf, VT, out, 2048, 2048, 2048, 1024,
        2048L * 2048, 1024L * 2048, 2048L * 1024, nullptr, nullptr, 1.0f);

    (void)in_sizes; (void)n_in; (void)out_size; (void)ws_size;
}

// Round 4
// 280.536 us; speedup vs baseline: 1.2750x; 1.0633x over previous
//
#include <hip/hip_runtime.h>
#include <cstdint>

using u16 = unsigned short;
using u32 = unsigned int;

typedef __attribute__((ext_vector_type(8))) short short8;   // 8 bf16 (A/B frag)
typedef __attribute__((ext_vector_type(4))) float floatx4;  // C frag

__device__ __forceinline__ u16 f2bf(float f) {
    u32 u = __float_as_uint(f);
    u32 r = u + 0x7fffu + ((u >> 16) & 1u);   // round-to-nearest-even
    return (u16)(r >> 16);
}
__device__ __forceinline__ float bf2f(u16 h) {
    return __uint_as_float(((u32)h) << 16);
}

// ---------------------------------------------------------------- converts
__global__ void cvt_f32_to_bf16(const float* __restrict__ in, u16* __restrict__ out, long n) {
    long i = ((long)blockIdx.x * blockDim.x + threadIdx.x) * 4;
    if (i >= n) return;
    float4 v = *reinterpret_cast<const float4*>(in + i);
    uint2 o;
    o.x = (u32)f2bf(v.x) | ((u32)f2bf(v.y) << 16);
    o.y = (u32)f2bf(v.z) | ((u32)f2bf(v.w) << 16);
    *reinterpret_cast<uint2*>(out + i) = o;
}

// three 1024x1024 weight matrices + the q|k bias concat in one dispatch
__global__ void cvt3(const float* __restrict__ w0, const float* __restrict__ w1,
                     const float* __restrict__ w2,
                     u16* __restrict__ o0, u16* __restrict__ o1, u16* __restrict__ o2,
                     const float* __restrict__ qb, const float* __restrict__ kb,
                     float* __restrict__ bqk) {
    int b = blockIdx.x;            // 3080 blocks
    if (b >= 3072) {               // bias concat: 8 blocks x 256 = 2048
        int i = (b - 3072) * 256 + threadIdx.x;
        bqk[i] = (i < 1024) ? qb[i] : kb[i - 1024];
        return;
    }
    int seg = b >> 10;
    const float* src; u16* dst;
    if (seg == 0)      { src = w0; dst = o0; }
    else if (seg == 1) { src = w1; dst = o1; }
    else               { src = w2; dst = o2; }
    long i = ((long)(b & 1023) * 256 + threadIdx.x) * 4;
    float4 v = *reinterpret_cast<const float4*>(src + i);
    uint2 o;
    o.x = (u32)f2bf(v.x) | ((u32)f2bf(v.y) << 16);
    o.y = (u32)f2bf(v.z) | ((u32)f2bf(v.w) << 16);
    *reinterpret_cast<uint2*>(dst + i) = o;
}

// ---------------------------------------------------------------- GEMM (NT)
// C[m][n] = scale * sum_k A[m][k]*B[n][k] + bias_col[n] + bias_row[m], optional fused RoPE
// 128x128 tile, BK=64 (two 32-wide LDS panels), 256 threads,
// 4 waves each 64x64 via 4x4 of 16x16x32 MFMA, 2 k-chunks per barrier pair.
// XCD swizzle: HW round-robins linear block id % 8 across XCDs; remap so each
// XCD gets a CONTIGUOUS chunk of id-space -> blocks sharing an A-panel share L2.
__device__ __forceinline__ void async_cp16(const u16* g, u16* l) {
    __builtin_amdgcn_global_load_lds(
        (const __attribute__((address_space(1))) void*)g,
        (__attribute__((address_space(3))) void*)l, 16, 0, 0);
}

template <bool BF16_OUT, bool ROPE>
__global__ __launch_bounds__(256)
void gemm_nt(const u16* __restrict__ A, const u16* __restrict__ B, void* __restrict__ Cv,
             int K, int lda, int ldb, int ldc,
             long sA, long sB, long sC,
             const float* __restrict__ bias_col, const float* __restrict__ bias_row,
             float scale)
{
    // ---- XCD-aware block remap (perf heuristic only) ----
    const u32 gx = gridDim.x, gy = gridDim.y;
    u32 id = blockIdx.x + gx * (blockIdx.y + gy * blockIdx.z);
    const u32 G = gx * gy * gridDim.z;
    if ((G & 7u) == 0u) {
        id = (id & 7u) * (G >> 3) + (id >> 3);
    }
    const u32 bx = id % gx;
    const u32 t1 = id / gx;
    const u32 by = t1 % gy;
    const u32 bz = t1 / gy;

    A += (long)bz * sA;
    B += (long)bz * sB;
    const long cbase = (long)bz * sC;

    // LDS 32KB: A = 2 panels of [128][32] u16, B likewise. Epilogue transpose
    // buffer (4 waves x 16 x 68 f32 = 17.4KB) aliases the same memory.
    __shared__ alignas(16) u16 smem[16384];
    u16* As = smem;                 // panels: As + p*4096
    u16* Bs = smem + 8192;

    const int tid  = threadIdx.x;
    const int lane = tid & 63;
    const int wave = tid >> 6;
    const int wm = (wave >> 1) << 6;   // wave row offset in tile
    const int wn = (wave & 1) << 6;    // wave col offset in tile

    const long tile_m = (long)by * 128;
    const long tile_n = (long)bx * 128;

    floatx4 acc[4][4] = {};

    // staging: thread t loads 16B (8 bf16): row = t>>2, k-part = (t&3)*8 within a panel
    const int srow = tid >> 2;
    const int skp  = (tid & 3) * 8;
    const u16* Ag = A + (tile_m + srow) * (long)lda + skp;
    const u16* Bg = B + (tile_n + srow) * (long)ldb + skp;
    u16* Asl = &As[tid * 8];           // wave-contiguous (global_load_lds requirement)
    u16* Bsl = &Bs[tid * 8];

    const int fm = lane & 15;
    const int fk = (lane >> 4) * 8;

    for (int k0 = 0; k0 < K; k0 += 64) {
        // panel 0 (k0..k0+31) and panel 1 (k0+32..k0+63): 8 async 16B copies
        async_cp16(Ag,                       Asl);
        async_cp16(Ag + 64 * (long)lda,      Asl + 64 * 32);
        async_cp16(Ag + 32,                  Asl + 4096);
        async_cp16(Ag + 32 + 64 * (long)lda, Asl + 4096 + 64 * 32);
        async_cp16(Bg,                       Bsl);
        async_cp16(Bg + 64 * (long)ldb,      Bsl + 64 * 32);
        async_cp16(Bg + 32,                  Bsl + 4096);
        async_cp16(Bg + 32 + 64 * (long)ldb, Bsl + 4096 + 64 * 32);
        Ag += 64; Bg += 64;
        __syncthreads();   // one vmcnt drain + barrier per 32 MFMA

        #pragma unroll
        for (int c = 0; c < 2; ++c) {
            const u16* Ap = As + c * 4096;
            const u16* Bp = Bs + c * 4096;
            short8 af[4], bfr[4];
            #pragma unroll
            for (int i = 0; i < 4; ++i)
                af[i] = *reinterpret_cast<const short8*>(&Ap[(wm + i * 16 + fm) * 32 + fk]);
            #pragma unroll
            for (int j = 0; j < 4; ++j)
                bfr[j] = *reinterpret_cast<const short8*>(&Bp[(wn + j * 16 + fm) * 32 + fk]);
            #pragma unroll
            for (int i = 0; i < 4; ++i)
                #pragma unroll
                for (int j = 0; j < 4; ++j)
                    acc[i][j] = __builtin_amdgcn_mfma_f32_16x16x32_bf16(af[i], bfr[j], acc[i][j], 0, 0, 0);
        }
        __syncthreads();
    }

    // ---------------- epilogue: LDS transpose -> vectorized stores ----------------
    // C/D layout: col = lane&15, row = (lane>>4)*4 + r
    const int q4  = lane >> 4;
    const int c16 = lane & 15;
    float* smemf  = (float*)smem;
    float* myeps = smemf + wave * (16 * 68);
    const long n0 = tile_n + wn + c16 * 4;    // 4 consecutive columns per lane (lane-constant)

    float4 bc4 = make_float4(0.f, 0.f, 0.f, 0.f);
    if (bias_col) bc4 = *reinterpret_cast<const float4*>(bias_col + n0);

    float inv0 = 0.f, inv1 = 0.f;
    if constexpr (ROPE) {
        // inv_freq = 10000^(-i/512); pair index i = ((n>>1) & 511), lane-constant
        int p0 = (int)(n0 >> 1);
        inv0 = __expf((float)(p0 & 511)       * -1.79889463e-2f);
        inv1 = __expf((float)((p0 + 1) & 511) * -1.79889463e-2f);
    }

    #pragma unroll
    for (int i = 0; i < 4; ++i) {
        __syncthreads();   // protect As/Bs (first) / previous chunk reads
        #pragma unroll
        for (int j = 0; j < 4; ++j)
            #pragma unroll
            for (int r = 0; r < 4; ++r)
                myeps[(q4 * 4 + r) * 68 + j * 16 + c16] = acc[i][j][r];
        __syncthreads();
        #pragma unroll
        for (int p = 0; p < 4; ++p) {
            int lrow = p * 4 + q4;
            long m = tile_m + wm + i * 16 + lrow;
            float4 v = *reinterpret_cast<const float4*>(&myeps[lrow * 68 + c16 * 4]);
            v.x = v.x * scale + bc4.x;
            v.y = v.y * scale + bc4.y;
            v.z = v.z * scale + bc4.z;
            v.w = v.w * scale + bc4.w;
            if (bias_row) {
                float br = bias_row[m];
                v.x += br; v.y += br; v.z += br; v.w += br;
            }
            if constexpr (ROPE) {
                int s = (int)(m & 2047);
                float a0 = (float)s * inv0, a1 = (float)s * inv1;
                float sn0 = __sinf(a0), cs0 = __cosf(a0);
                float sn1 = __sinf(a1), cs1 = __cosf(a1);
                float x0 = v.x, x1 = v.y, x2 = v.z, x3 = v.w;
                v.x = x0 * cs0 - x1 * sn0;
                v.y = x0 * sn0 + x1 * cs0;
                v.z = x2 * cs1 - x3 * sn1;
                v.w = x2 * sn1 + x3 * cs1;
            }
            long off = cbase + m * (long)ldc + n0;
            if constexpr (BF16_OUT) {
                uint2 o;
                o.x = (u32)f2bf(v.x) | ((u32)f2bf(v.y) << 16);
                o.y = (u32)f2bf(v.z) | ((u32)f2bf(v.w) << 16);
                *reinterpret_cast<uint2*>((u16*)Cv + off) = o;
            } else {
                *reinterpret_cast<float4*>((float*)Cv + off) = v;
            }
        }
    }
}

// ---------------------------------------------------------------- softmax rows of 2048 (bf16 in, bf16 out)
__global__ __launch_bounds__(256)
void softmax_kernel(const u16* __restrict__ S, u16* __restrict__ P) {
    long row = blockIdx.x;
    const u16* s = S + row * 2048;
    u16* p = P + row * 2048;
    int tid = threadIdx.x;
    uint4 raw = *reinterpret_cast<const uint4*>(s + tid * 8);
    float v[8];
    v[0] = bf2f((u16)(raw.x & 0xffffu)); v[1] = bf2f((u16)(raw.x >> 16));
    v[2] = bf2f((u16)(raw.y & 0xffffu)); v[3] = bf2f((u16)(raw.y >> 16));
    v[4] = bf2f((u16)(raw.z & 0xffffu)); v[5] = bf2f((u16)(raw.z >> 16));
    v[6] = bf2f((u16)(raw.w & 0xffffu)); v[7] = bf2f((u16)(raw.w >> 16));
    float mx = v[0];
    #pragma unroll
    for (int j = 1; j < 8; ++j) mx = fmaxf(mx, v[j]);
    #pragma unroll
    for (int off = 32; off; off >>= 1) mx = fmaxf(mx, __shfl_xor(mx, off));
    __shared__ float redm[4];
    __shared__ float reds[4];
    int lane = tid & 63, wv = tid >> 6;
    if (lane == 0) redm[wv] = mx;
    __syncthreads();
    mx = fmaxf(fmaxf(redm[0], redm[1]), fmaxf(redm[2], redm[3]));
    float sum = 0.0f;
    #pragma unroll
    for (int j = 0; j < 8; ++j) { v[j] = __expf(v[j] - mx); sum += v[j]; }
    #pragma unroll
    for (int off = 32; off; off >>= 1) sum += __shfl_xor(sum, off);
    if (lane == 0) reds[wv] = sum;
    __syncthreads();
    sum = reds[0] + reds[1] + reds[2] + reds[3];
    float inv = 1.0f / sum;
    uint4 o;
    o.x = (u32)f2bf(v[0] * inv) | ((u32)f2bf(v[1] * inv) << 16);
    o.y = (u32)f2bf(v[2] * inv) | ((u32)f2bf(v[3] * inv) << 16);
    o.z = (u32)f2bf(v[4] * inv) | ((u32)f2bf(v[5] * inv) << 16);
    o.w = (u32)f2bf(v[6] * inv) | ((u32)f2bf(v[7] * inv) << 16);
    *reinterpret_cast<uint4*>(&p[tid * 8]) = o;
}

// ---------------------------------------------------------------- launch
extern "C" void kernel_launch(void* const* d_in, const int* in_sizes, int n_in,
                              void* d_out, int out_size, void* d_ws, size_t ws_size,
                              hipStream_t stream)
{
    const float* x   = (const float*)d_in[0];
    const float* wqw = (const float*)d_in[1];
    const float* wqb = (const float*)d_in[2];
    const float* wkw = (const float*)d_in[3];
    const float* wkb = (const float*)d_in[4];
    const float* wvw = (const float*)d_in[5];
    const float* wvb = (const float*)d_in[6];
    float* out = (float*)d_out;

    char* ws = (char*)d_ws;
    const size_t MB = 1ull << 20;
    // late-phase buffers
    u16*   Sbuf = (u16*)(ws + 0);            // 32MB [4][2048][2048] bf16  (written at G3)
    u16*   Pbuf = (u16*)(ws + 64 * MB);      // 32MB [4][2048][2048] bf16
    u16*   QK   = (u16*)(ws + 96 * MB);      // 32MB [8192][2048] bf16 (Q | K), RoPE applied
    u16*   VT   = (u16*)(ws + 128 * MB);     // 16MB [4][1024][2048] bf16 (V transposed)
    // early-phase buffers (overlap Sbuf region; dead before G3 writes S)
    u16*   xb    = (u16*)(ws + 0);           // 16MB [8192][1024]
    u16*   wqk   = (u16*)(ws + 16 * MB);     //  4MB [2048][1024]
    u16*   wvbuf = (u16*)(ws + 20 * MB);     //  2MB [1024][1024]
    float* bqk   = (float*)(ws + 22 * MB);   //  8KB [2048]

    // 1. dtype conversion (+ bias concat fused into cvt3)
    cvt_f32_to_bf16<<<dim3(8192), 256, 0, stream>>>(x, xb, 8192L * 1024);
    cvt3<<<dim3(3080), 256, 0, stream>>>(wqw, wkw, wvw, wqk, wqk + 1024 * 1024, wvbuf,
                                         wqb, wkb, bqk);

    // 2. G1: [Q|K] = xb @ wqk^T + bqk, RoPE fused in epilogue  (M=8192, N=2048, K=1024)
    gemm_nt<true, true><<<dim3(16, 64, 1), 256, 0, stream>>>(
        xb, wqk, QK, 1024, 1024, 1024, 2048,
        0L, 0L, 0L, bqk, nullptr, 1.0f);

    // 3. G2: VT[b] = wv @ xb[b]^T + bv[row]   (M=1024, N=2048, K=1024, z=4)
    gemm_nt<true, false><<<dim3(16, 8, 4), 256, 0, stream>>>(
        wvbuf, xb, VT, 1024, 1024, 1024, 2048,
        0L, 2048L * 1024, 1024L * 2048, nullptr, wvb, 1.0f);

    // 4. G3: S[b] = Q[b] @ K[b]^T / 32 -> bf16   (M=N=2048, K=1024, z=4)
    gemm_nt<true, false><<<dim3(16, 16, 4), 256, 0, stream>>>(
        QK, QK + 1024, Sbuf, 1024, 2048, 2048, 2048,
        2048L * 2048, 2048L * 2048, 2048L * 2048, nullptr, nullptr, 0.03125f);

    // 5. softmax rows (bf16 in) -> P bf16
    softmax_kernel<<<dim3(8192), 256, 0, stream>>>(Sbuf, Pbuf);

    // 6. G5: out[b] = P[b] @ VT[b]^T   (M=2048, N=1024, K=2048, z=4)
    gemm_nt<false, false><<<dim3(8, 16, 4), 256, 0, stream>>>(
        Pbuf, VT, out, 2048, 2048, 2048, 1024,
        2048L * 2048, 1024L * 2048, 2048L * 1024, nullptr, nullptr, 1.0f);

    (void)in_sizes; (void)n_in; (void)out_size; (void)ws_size;
}

// Round 5
// 272.821 us; speedup vs baseline: 1.3111x; 1.0283x over previous
//
#include <hip/hip_runtime.h>
#include <cstdint>

using u16 = unsigned short;
using u32 = unsigned int;

typedef __attribute__((ext_vector_type(8))) short short8;   // 8 bf16 (A/B frag)
typedef __attribute__((ext_vector_type(4))) float floatx4;  // C frag

__device__ __forceinline__ u16 f2bf(float f) {
    u32 u = __float_as_uint(f);
    u32 r = u + 0x7fffu + ((u >> 16) & 1u);   // round-to-nearest-even
    return (u16)(r >> 16);
}
__device__ __forceinline__ float bf2f(u16 h) {
    return __uint_as_float(((u32)h) << 16);
}

// ---------------------------------------------------------------- converts
__global__ void cvt_f32_to_bf16(const float* __restrict__ in, u16* __restrict__ out, long n) {
    long i = ((long)blockIdx.x * blockDim.x + threadIdx.x) * 4;
    if (i >= n) return;
    float4 v = *reinterpret_cast<const float4*>(in + i);
    uint2 o;
    o.x = (u32)f2bf(v.x) | ((u32)f2bf(v.y) << 16);
    o.y = (u32)f2bf(v.z) | ((u32)f2bf(v.w) << 16);
    *reinterpret_cast<uint2*>(out + i) = o;
}

// three 1024x1024 weight matrices + the q|k bias concat in one dispatch
__global__ void cvt3(const float* __restrict__ w0, const float* __restrict__ w1,
                     const float* __restrict__ w2,
                     u16* __restrict__ o0, u16* __restrict__ o1, u16* __restrict__ o2,
                     const float* __restrict__ qb, const float* __restrict__ kb,
                     float* __restrict__ bqk) {
    int b = blockIdx.x;            // 3080 blocks
    if (b >= 3072) {               // bias concat: 8 blocks x 256 = 2048
        int i = (b - 3072) * 256 + threadIdx.x;
        bqk[i] = (i < 1024) ? qb[i] : kb[i - 1024];
        return;
    }
    int seg = b >> 10;
    const float* src; u16* dst;
    if (seg == 0)      { src = w0; dst = o0; }
    else if (seg == 1) { src = w1; dst = o1; }
    else               { src = w2; dst = o2; }
    long i = ((long)(b & 1023) * 256 + threadIdx.x) * 4;
    float4 v = *reinterpret_cast<const float4*>(src + i);
    uint2 o;
    o.x = (u32)f2bf(v.x) | ((u32)f2bf(v.y) << 16);
    o.y = (u32)f2bf(v.z) | ((u32)f2bf(v.w) << 16);
    *reinterpret_cast<uint2*>(dst + i) = o;
}

// ---------------------------------------------------------------- GEMM core (NT)
// C[m][n] = scale * sum_k A[m][k]*B[n][k] + bias_col[n] + bias_row[m], optional RoPE.
// 128x128 tile, BK=64 (two 32-wide LDS panels), 256 threads.
// LDS bank swizzle: 16B chunk (row,kp) lives at slot row*4 + (kp ^ (row&3)).
// Staging keeps wave-contiguous DMA dests and permutes the *global* k-offset;
// fragment reads apply the same XOR -> residues mod 8 uniform -> conflict-free.
__device__ __forceinline__ void async_cp16(const u16* g, u16* l) {
    __builtin_amdgcn_global_load_lds(
        (const __attribute__((address_space(1))) void*)g,
        (__attribute__((address_space(3))) void*)l, 16, 0, 0);
}

template <bool BF16_OUT>
__device__ __forceinline__ void gemm_core(
    const u16* __restrict__ A, const u16* __restrict__ B, void* __restrict__ Cv,
    int K, int lda, int ldb, int ldc,
    long tile_m, long tile_n, long cbase,
    const float* bias_col, const float* bias_row,
    float scale, bool rope, u16* smem)
{
    u16* As = smem;                 // panels: As + p*4096
    u16* Bs = smem + 8192;

    const int tid  = threadIdx.x;
    const int lane = tid & 63;
    const int wave = tid >> 6;
    const int wm = (wave >> 1) << 6;   // wave row offset in tile
    const int wn = (wave & 1) << 6;    // wave col offset in tile

    floatx4 acc[4][4] = {};

    // staging: thread t -> LDS slot t (16B units); global (row = t>>2,
    // kp = (t&3) ^ (row&3))  [bijective per row, same row&3 for row+64]
    const int srow = tid >> 2;
    const int skp  = (((tid & 3) ^ (srow & 3))) * 8;
    const u16* Ag = A + (tile_m + srow) * (long)lda + skp;
    const u16* Bg = B + (tile_n + srow) * (long)ldb + skp;
    u16* Asl = &As[tid * 8];           // wave-contiguous (global_load_lds requirement)
    u16* Bsl = &Bs[tid * 8];

    const int fm  = lane & 15;
    const int fks = (((lane >> 4) ^ (lane & 3))) * 8;   // swizzled k-offset

    for (int k0 = 0; k0 < K; k0 += 64) {
        // panel 0 (k0..k0+31) and panel 1 (k0+32..k0+63): 8 async 16B copies
        async_cp16(Ag,                       Asl);
        async_cp16(Ag + 64 * (long)lda,      Asl + 64 * 32);
        async_cp16(Ag + 32,                  Asl + 4096);
        async_cp16(Ag + 32 + 64 * (long)lda, Asl + 4096 + 64 * 32);
        async_cp16(Bg,                       Bsl);
        async_cp16(Bg + 64 * (long)ldb,      Bsl + 64 * 32);
        async_cp16(Bg + 32,                  Bsl + 4096);
        async_cp16(Bg + 32 + 64 * (long)ldb, Bsl + 4096 + 64 * 32);
        Ag += 64; Bg += 64;
        __syncthreads();   // one vmcnt drain + barrier per 32 MFMA

        #pragma unroll
        for (int c = 0; c < 2; ++c) {
            const u16* Ap = As + c * 4096;
            const u16* Bp = Bs + c * 4096;
            short8 af[4], bfr[4];
            #pragma unroll
            for (int i = 0; i < 4; ++i)
                af[i] = *reinterpret_cast<const short8*>(&Ap[(wm + i * 16 + fm) * 32 + fks]);
            #pragma unroll
            for (int j = 0; j < 4; ++j)
                bfr[j] = *reinterpret_cast<const short8*>(&Bp[(wn + j * 16 + fm) * 32 + fks]);
            #pragma unroll
            for (int i = 0; i < 4; ++i)
                #pragma unroll
                for (int j = 0; j < 4; ++j)
                    acc[i][j] = __builtin_amdgcn_mfma_f32_16x16x32_bf16(af[i], bfr[j], acc[i][j], 0, 0, 0);
        }
        __syncthreads();
    }

    // ---------------- epilogue: LDS transpose -> vectorized stores ----------------
    // C/D layout: col = lane&15, row = (lane>>4)*4 + r
    const int q4  = lane >> 4;
    const int c16 = lane & 15;
    float* smemf  = (float*)smem;
    float* myeps = smemf + wave * (16 * 68);
    const long n0 = tile_n + wn + c16 * 4;    // 4 consecutive columns per lane (lane-constant)

    float4 bc4 = make_float4(0.f, 0.f, 0.f, 0.f);
    if (bias_col) bc4 = *reinterpret_cast<const float4*>(bias_col + n0);

    float inv0 = 0.f, inv1 = 0.f;
    if (rope) {
        // inv_freq = 10000^(-i/512); pair index i = ((n>>1) & 511), lane-constant
        int p0 = (int)(n0 >> 1);
        inv0 = __expf((float)(p0 & 511)       * -1.79889463e-2f);
        inv1 = __expf((float)((p0 + 1) & 511) * -1.79889463e-2f);
    }

    #pragma unroll
    for (int i = 0; i < 4; ++i) {
        __syncthreads();   // protect As/Bs (first) / previous chunk reads
        #pragma unroll
        for (int j = 0; j < 4; ++j)
            #pragma unroll
            for (int r = 0; r < 4; ++r)
                myeps[(q4 * 4 + r) * 68 + j * 16 + c16] = acc[i][j][r];
        __syncthreads();
        #pragma unroll
        for (int p = 0; p < 4; ++p) {
            int lrow = p * 4 + q4;
            long m = tile_m + wm + i * 16 + lrow;
            float4 v = *reinterpret_cast<const float4*>(&myeps[lrow * 68 + c16 * 4]);
            v.x = v.x * scale + bc4.x;
            v.y = v.y * scale + bc4.y;
            v.z = v.z * scale + bc4.z;
            v.w = v.w * scale + bc4.w;
            if (bias_row) {
                float br = bias_row[m];
                v.x += br; v.y += br; v.z += br; v.w += br;
            }
            if (rope) {
                int s = (int)(m & 2047);
                float a0 = (float)s * inv0, a1 = (float)s * inv1;
                float sn0 = __sinf(a0), cs0 = __cosf(a0);
                float sn1 = __sinf(a1), cs1 = __cosf(a1);
                float x0 = v.x, x1 = v.y, x2 = v.z, x3 = v.w;
                v.x = x0 * cs0 - x1 * sn0;
                v.y = x0 * sn0 + x1 * cs0;
                v.z = x2 * cs1 - x3 * sn1;
                v.w = x2 * sn1 + x3 * cs1;
            }
            long off = cbase + m * (long)ldc + n0;
            if constexpr (BF16_OUT) {
                uint2 o;
                o.x = (u32)f2bf(v.x) | ((u32)f2bf(v.y) << 16);
                o.y = (u32)f2bf(v.z) | ((u32)f2bf(v.w) << 16);
                *reinterpret_cast<uint2*>((u16*)Cv + off) = o;
            } else {
                *reinterpret_cast<float4*>((float*)Cv + off) = v;
            }
        }
    }
}

// 3D-grid wrapper with XCD-contiguous remap (used for G3, G5)
template <bool BF16_OUT>
__global__ __launch_bounds__(256)
void gemm_nt(const u16* __restrict__ A, const u16* __restrict__ B, void* __restrict__ Cv,
             int K, int lda, int ldb, int ldc,
             long sA, long sB, long sC,
             const float* __restrict__ bias_col, const float* __restrict__ bias_row,
             float scale)
{
    const u32 gx = gridDim.x, gy = gridDim.y;
    u32 id = blockIdx.x + gx * (blockIdx.y + gy * blockIdx.z);
    const u32 G = gx * gy * gridDim.z;
    if ((G & 7u) == 0u) id = (id & 7u) * (G >> 3) + (id >> 3);
    const u32 bx = id % gx;
    const u32 t1 = id / gx;
    const u32 by = t1 % gy;
    const u32 bz = t1 / gy;

    __shared__ alignas(16) u16 smem[16384];
    gemm_core<BF16_OUT>(A + (long)bz * sA, B + (long)bz * sB, Cv,
                        K, lda, ldb, ldc,
                        (long)by * 128, (long)bx * 128, (long)bz * sC,
                        bias_col, bias_row, scale, false, smem);
}

// fused G1 (QK-proj + RoPE) and G2 (V^T proj): 1536 blocks, 1D grid
__global__ __launch_bounds__(256)
void gemm_fused12(const u16* __restrict__ xb, const u16* __restrict__ wqk,
                  const u16* __restrict__ wv, u16* __restrict__ QK, u16* __restrict__ VT,
                  const float* __restrict__ bqk, const float* __restrict__ wvb)
{
    u32 id = blockIdx.x;                       // 1536
    id = (id & 7u) * 192u + (id >> 3);         // XCD-contiguous remap
    __shared__ alignas(16) u16 smem[16384];
    if (id < 1024u) {
        // G1: [Q|K] = xb @ wqk^T + bqk, RoPE (M=8192, N=2048, K=1024)
        u32 bx = id & 15u, by = id >> 4;
        gemm_core<true>(xb, wqk, QK, 1024, 1024, 1024, 2048,
                        (long)by * 128, (long)bx * 128, 0L,
                        bqk, nullptr, 1.0f, true, smem);
    } else {
        // G2: VT[b] = wv @ xb[b]^T + bv[row] (M=1024, N=2048, K=1024, z=4)
        u32 r = id - 1024u;
        u32 bx = r & 15u, by = (r >> 4) & 7u, bz = r >> 7;
        gemm_core<true>(wv, xb + (long)bz * 2048 * 1024, VT,
                        1024, 1024, 1024, 2048,
                        (long)by * 128, (long)bx * 128, (long)bz * 1024 * 2048,
                        nullptr, wvb, 1.0f, false, smem);
    }
}

// ---------------------------------------------------------------- softmax rows of 2048 (bf16 in, bf16 out)
__global__ __launch_bounds__(256)
void softmax_kernel(const u16* __restrict__ S, u16* __restrict__ P) {
    long row = blockIdx.x;
    const u16* s = S + row * 2048;
    u16* p = P + row * 2048;
    int tid = threadIdx.x;
    uint4 raw = *reinterpret_cast<const uint4*>(s + tid * 8);
    float v[8];
    v[0] = bf2f((u16)(raw.x & 0xffffu)); v[1] = bf2f((u16)(raw.x >> 16));
    v[2] = bf2f((u16)(raw.y & 0xffffu)); v[3] = bf2f((u16)(raw.y >> 16));
    v[4] = bf2f((u16)(raw.z & 0xffffu)); v[5] = bf2f((u16)(raw.z >> 16));
    v[6] = bf2f((u16)(raw.w & 0xffffu)); v[7] = bf2f((u16)(raw.w >> 16));
    float mx = v[0];
    #pragma unroll
    for (int j = 1; j < 8; ++j) mx = fmaxf(mx, v[j]);
    #pragma unroll
    for (int off = 32; off; off >>= 1) mx = fmaxf(mx, __shfl_xor(mx, off));
    __shared__ float redm[4];
    __shared__ float reds[4];
    int lane = tid & 63, wv = tid >> 6;
    if (lane == 0) redm[wv] = mx;
    __syncthreads();
    mx = fmaxf(fmaxf(redm[0], redm[1]), fmaxf(redm[2], redm[3]));
    float sum = 0.0f;
    #pragma unroll
    for (int j = 0; j < 8; ++j) { v[j] = __expf(v[j] - mx); sum += v[j]; }
    #pragma unroll
    for (int off = 32; off; off >>= 1) sum += __shfl_xor(sum, off);
    if (lane == 0) reds[wv] = sum;
    __syncthreads();
    sum = reds[0] + reds[1] + reds[2] + reds[3];
    float inv = 1.0f / sum;
    uint4 o;
    o.x = (u32)f2bf(v[0] * inv) | ((u32)f2bf(v[1] * inv) << 16);
    o.y = (u32)f2bf(v[2] * inv) | ((u32)f2bf(v[3] * inv) << 16);
    o.z = (u32)f2bf(v[4] * inv) | ((u32)f2bf(v[5] * inv) << 16);
    o.w = (u32)f2bf(v[6] * inv) | ((u32)f2bf(v[7] * inv) << 16);
    *reinterpret_cast<uint4*>(&p[tid * 8]) = o;
}

// ---------------------------------------------------------------- launch
extern "C" void kernel_launch(void* const* d_in, const int* in_sizes, int n_in,
                              void* d_out, int out_size, void* d_ws, size_t ws_size,
                              hipStream_t stream)
{
    const float* x   = (const float*)d_in[0];
    const float* wqw = (const float*)d_in[1];
    const float* wqb = (const float*)d_in[2];
    const float* wkw = (const float*)d_in[3];
    const float* wkb = (const float*)d_in[4];
    const float* wvw = (const float*)d_in[5];
    const float* wvb = (const float*)d_in[6];
    float* out = (float*)d_out;

    char* ws = (char*)d_ws;
    const size_t MB = 1ull << 20;
    // late-phase buffers
    u16*   Sbuf = (u16*)(ws + 0);            // 32MB [4][2048][2048] bf16  (written at G3)
    u16*   Pbuf = (u16*)(ws + 64 * MB);      // 32MB [4][2048][2048] bf16
    u16*   QK   = (u16*)(ws + 96 * MB);      // 32MB [8192][2048] bf16 (Q | K), RoPE applied
    u16*   VT   = (u16*)(ws + 128 * MB);     // 16MB [4][1024][2048] bf16 (V transposed)
    // early-phase buffers (overlap Sbuf region; dead before G3 writes S)
    u16*   xb    = (u16*)(ws + 0);           // 16MB [8192][1024]
    u16*   wqk   = (u16*)(ws + 16 * MB);     //  4MB [2048][1024]
    u16*   wvbuf = (u16*)(ws + 20 * MB);     //  2MB [1024][1024]
    float* bqk   = (float*)(ws + 22 * MB);   //  8KB [2048]

    // 1. dtype conversion (+ bias concat fused into cvt3)
    cvt_f32_to_bf16<<<dim3(8192), 256, 0, stream>>>(x, xb, 8192L * 1024);
    cvt3<<<dim3(3080), 256, 0, stream>>>(wqw, wkw, wvw, wqk, wqk + 1024 * 1024, wvbuf,
                                         wqb, wkb, bqk);

    // 2. fused G1 + G2
    gemm_fused12<<<dim3(1536), 256, 0, stream>>>(xb, wqk, wvbuf, QK, VT, bqk, wvb);

    // 3. G3: S[b] = Q[b] @ K[b]^T / 32 -> bf16   (M=N=2048, K=1024, z=4)
    gemm_nt<true><<<dim3(16, 16, 4), 256, 0, stream>>>(
        QK, QK + 1024, Sbuf, 1024, 2048, 2048, 2048,
        2048L * 2048, 2048L * 2048, 2048L * 2048, nullptr, nullptr, 0.03125f);

    // 4. softmax rows (bf16 in) -> P bf16
    softmax_kernel<<<dim3(8192), 256, 0, stream>>>(Sbuf, Pbuf);

    // 5. G5: out[b] = P[b] @ VT[b]^T   (M=2048, N=1024, K=2048, z=4)
    gemm_nt<false><<<dim3(8, 16, 4), 256, 0, stream>>>(
        Pbuf, VT, out, 2048, 2048, 2048, 1024,
        2048L * 2048, 1024L * 2048, 2048L * 1024, nullptr, nullptr, 1.0f);

    (void)in_sizes; (void)n_in; (void)out_size; (void)ws_size;
}